// Round 1
// baseline (1108.762 us; speedup 1.0000x reference)
//
#include <hip/hip_runtime.h>
#include <math.h>

#define NB 2
#define HB 8
#define LB 2048
#define EB 64
#define BITSN 32
#define CLN 128
#define ITERS 10
#define TOPKN 32
#define NEGV -10000000.0f

// ---------------------------------------------------------------------------
// Kernel 1: LSH bits. One wave handles 2 queries; lane = 32*which + b.
// bits[(n*H+h)*L + l] = bitmask over 32 planes of (dot([Q,1], plane_b) > 0).
// Double accumulation: the >0 decision is discrete; double matches the true
// sign essentially surely.
// ---------------------------------------------------------------------------
__global__ __launch_bounds__(256) void bits_kernel(const float* __restrict__ q,
                                                   const float* __restrict__ planes,
                                                   unsigned int* __restrict__ bits) {
    int tid = threadIdx.x;
    int wave = tid >> 6;
    int lane = tid & 63;
    int b = lane & 31;
    int which = lane >> 5;
    int qi = blockIdx.x * 8 + wave * 2 + which;   // qi = (n*H + h)*L + l
    int l = qi & (LB - 1);
    int nh = qi / LB;
    int h = nh & (HB - 1);
    int n = nh / HB;
    const float* qrow = q + (((long long)n * LB + l) * HB + h) * EB;  // queries (N,L,H,E)
    const float* prow = planes + b * (EB + 1);
    double acc = (double)prow[EB];                 // bias (the concatenated ones column)
    #pragma unroll 8
    for (int e = 0; e < EB; ++e) acc += (double)qrow[e] * (double)prow[e];
    unsigned long long m = __ballot(acc > 0.0);
    if (b == 0) {
        bits[qi] = (unsigned int)(which ? (m >> 32) : (m & 0xffffffffULL));
    }
}

// ---------------------------------------------------------------------------
// Kernel 2: k-means on Hamming distance. One block per (n,h). All integer /
// exact. argmin = first occurrence of min (scan c ascending, strict <).
// Centroid update bit: sums/max(cnt,1) >= 0.5  <=>  2*sums >= cnt (exact).
// ---------------------------------------------------------------------------
__global__ __launch_bounds__(1024) void cluster_kernel(const unsigned int* __restrict__ bits,
                                                       int* __restrict__ assign_g,
                                                       int* __restrict__ cnt_g) {
    __shared__ unsigned int bl[LB];
    __shared__ unsigned int cent[CLN];
    __shared__ int sums[CLN * BITSN];
    __shared__ int cnt[CLN];
    int nh = blockIdx.x;
    int tid = threadIdx.x;
    for (int l = tid; l < LB; l += 1024) bl[l] = bits[nh * LB + l];
    __syncthreads();
    if (tid < CLN) cent[tid] = bl[tid * (LB / CLN)];   // init_idx = c*L//C = 16c
    __syncthreads();

    for (int it = 0; it < ITERS; ++it) {
        for (int i = tid; i < CLN * BITSN; i += 1024) sums[i] = 0;
        if (tid < CLN) cnt[tid] = 0;
        __syncthreads();
        for (int l = tid; l < LB; l += 1024) {
            unsigned int bv = bl[l];
            int best = __popc(bv ^ cent[0]);
            int bc = 0;
            #pragma unroll 4
            for (int c = 1; c < CLN; ++c) {
                int d = __popc(bv ^ cent[c]);
                if (d < best) { best = d; bc = c; }
            }
            atomicAdd(&cnt[bc], 1);
            unsigned int bb = bv;
            while (bb) {
                int j = __ffs(bb) - 1;
                atomicAdd(&sums[bc * BITSN + j], 1);
                bb &= bb - 1;
            }
        }
        __syncthreads();
        if (tid < CLN) {
            int c = tid;
            int cn = cnt[c];
            if (cn > 0) {
                unsigned int nb = 0u;
                for (int j = 0; j < BITSN; ++j)
                    if (2 * sums[c * BITSN + j] >= cn) nb |= (1u << j);
                cent[c] = nb;
            }
        }
        __syncthreads();
    }

    // final (11th) assignment pass -> assign, cnt
    if (tid < CLN) cnt[tid] = 0;
    __syncthreads();
    for (int l = tid; l < LB; l += 1024) {
        unsigned int bv = bl[l];
        int best = __popc(bv ^ cent[0]);
        int bc = 0;
        #pragma unroll 4
        for (int c = 1; c < CLN; ++c) {
            int d = __popc(bv ^ cent[c]);
            if (d < best) { best = d; bc = c; }
        }
        assign_g[nh * LB + l] = bc;
        atomicAdd(&cnt[bc], 1);
    }
    __syncthreads();
    if (tid < CLN) cnt_g[nh * CLN + tid] = cnt[tid];
}

// ---------------------------------------------------------------------------
// Kernel 3: per-(n,h,c): Qg (deterministic double sums), QKc scores (double),
// top-32 with lower-index tie-break.
// ---------------------------------------------------------------------------
__global__ __launch_bounds__(256) void topk_kernel(const float* __restrict__ q,
                                                   const float* __restrict__ kk,
                                                   const int* __restrict__ assign_g,
                                                   const int* __restrict__ cnt_g,
                                                   int* __restrict__ tki) {
    __shared__ double qg[EB];
    __shared__ double psum[4][EB];
    __shared__ double s[LB];
    __shared__ double rv[256];
    __shared__ int ri[256];
    int bid = blockIdx.x;            // nh*128 + c
    int c = bid & (CLN - 1);
    int nh = bid >> 7;
    int h = nh & (HB - 1);
    int n = nh / HB;
    int tid = threadIdx.x;
    int e = tid & 63;
    int qq = tid >> 6;
    const int* arow = assign_g + nh * LB;

    // phase A: Qg = mean of Q rows assigned to cluster c (fixed quarter order)
    double acc = 0.0;
    int l0 = qq * (LB / 4), l1 = l0 + (LB / 4);
    for (int l = l0; l < l1; ++l) {
        if (arow[l] == c)
            acc += (double)q[(((long long)n * LB + l) * HB + h) * EB + e];
    }
    psum[qq][e] = acc;
    __syncthreads();
    if (tid < EB) {
        int cn = cnt_g[nh * CLN + c];
        double dcn = (double)(cn > 0 ? cn : 1);
        qg[tid] = (psum[0][tid] + psum[1][tid] + psum[2][tid] + psum[3][tid]) / dcn;
    }
    __syncthreads();

    // phase B: s[l] = dot(qg, K[l]); one wave per row, lane-parallel over e
    int wave = tid >> 6, lane = tid & 63;
    for (int l = wave; l < LB; l += 4) {
        double v = qg[lane] * (double)kk[(((long long)n * LB + l) * HB + h) * EB + lane];
        #pragma unroll
        for (int off = 32; off; off >>= 1) v += __shfl_xor(v, off);
        if (lane == 0) s[l] = v;
    }
    __syncthreads();

    // phase C: 32 rounds of block argmax (tie -> lower index)
    for (int r = 0; r < TOPKN; ++r) {
        double bv = -1.0e300;
        int bi = 0x7fffffff;
        for (int l = tid; l < LB; l += 256) {
            double v = s[l];
            if (v > bv || (v == bv && l < bi)) { bv = v; bi = l; }
        }
        rv[tid] = bv; ri[tid] = bi;
        __syncthreads();
        for (int off = 128; off; off >>= 1) {
            if (tid < off) {
                double ov = rv[tid + off]; int oi = ri[tid + off];
                if (ov > rv[tid] || (ov == rv[tid] && oi < ri[tid])) {
                    rv[tid] = ov; ri[tid] = oi;
                }
            }
            __syncthreads();
        }
        if (tid == 0) {
            tki[bid * TOPKN + r] = ri[0];
            s[ri[0]] = -1.0e300;
        }
        __syncthreads();
    }
}

// ---------------------------------------------------------------------------
// Kernel 4: gather attention. One wave per query (n,h,l).
// lanes 0..31 own keys (qk + softmax), then all 64 lanes own output dims.
// ---------------------------------------------------------------------------
__global__ __launch_bounds__(256) void attn_kernel(const float* __restrict__ q,
                                                   const float* __restrict__ kk,
                                                   const float* __restrict__ vv,
                                                   const int* __restrict__ assign_g,
                                                   const int* __restrict__ tki,
                                                   float* __restrict__ out) {
    int tid = threadIdx.x;
    int wave = tid >> 6, lane = tid & 63;
    int qi = blockIdx.x * 4 + wave;   // (nh)*L + l
    int l = qi & (LB - 1);
    int nh = qi / LB;
    int h = nh & (HB - 1);
    int n = nh / HB;
    int c = assign_g[qi];
    const int* krow = tki + (nh * CLN + c) * TOPKN;
    int j = lane & 31, p = lane >> 5;
    int kidx = krow[j];

    const float* qrow = q + (((long long)n * LB + l) * HB + h) * EB;
    const float* krp = kk + (((long long)n * LB + kidx) * HB + h) * EB;
    float part = 0.f;
    #pragma unroll
    for (int e = 32 * p; e < 32 * p + 32; ++e) part += qrow[e] * krp[e];
    // full dot, identical value on lanes j and j+32 (fixed lo+hi order)
    float qlo = __shfl(part, j);
    float qhi = __shfl(part, j + 32);
    float qk = qlo + qhi;

    bool future = kidx > l;
    float logit = 0.125f * (future ? NEGV : qk);
    float m = logit;
    #pragma unroll
    for (int off = 16; off; off >>= 1) m = fmaxf(m, __shfl_xor(m, off));
    float ex = expf(logit - m);
    float ssum = ex;
    #pragma unroll
    for (int off = 16; off; off >>= 1) ssum += __shfl_xor(ssum, off);
    float a = future ? 0.f : ex / ssum;

    // output accumulation: lane = output dim e
    const float* vbase = vv + ((long long)n * LB * HB + h) * EB;  // + ki*H*E + e
    float oacc = 0.f;
    #pragma unroll 4
    for (int jj = 0; jj < TOPKN; ++jj) {
        float aj = __shfl(a, jj);
        int kj = __shfl(kidx, jj);
        if (aj != 0.f)   // wave-uniform; 0*V contributes exactly 0 in ref too
            oacc += aj * vbase[(long long)kj * (HB * EB) + lane];
    }
    out[(((long long)n * LB + l) * HB + h) * EB + lane] = oacc;
}

// ---------------------------------------------------------------------------
extern "C" void kernel_launch(void* const* d_in, const int* in_sizes, int n_in,
                              void* d_out, int out_size, void* d_ws, size_t ws_size,
                              hipStream_t stream) {
    const float* q = (const float*)d_in[0];
    const float* k = (const float*)d_in[1];
    const float* v = (const float*)d_in[2];
    const float* planes = (const float*)d_in[3];
    float* out = (float*)d_out;

    const int NQ = NB * HB * LB;                  // 32768
    unsigned int* bits = (unsigned int*)d_ws;
    int* assign_g = (int*)((char*)d_ws + (size_t)NQ * 4);
    int* cnt_g = (int*)((char*)d_ws + (size_t)NQ * 8);
    int* tki = (int*)((char*)d_ws + (size_t)NQ * 8 + (size_t)NB * HB * CLN * 4);

    bits_kernel<<<NQ / 8, 256, 0, stream>>>(q, planes, bits);
    cluster_kernel<<<NB * HB, 1024, 0, stream>>>(bits, assign_g, cnt_g);
    topk_kernel<<<NB * HB * CLN, 256, 0, stream>>>(q, k, assign_g, cnt_g, tki);
    attn_kernel<<<NQ / 4, 256, 0, stream>>>(q, k, v, assign_g, tki, out);
}

// Round 2
// 536.953 us; speedup vs baseline: 2.0649x; 2.0649x over previous
//
#include <hip/hip_runtime.h>
#include <math.h>

#define NB 2
#define HB 8
#define LB 2048
#define EB 64
#define BITSN 32
#define CLN 128
#define ITERS 10
#define TOPKN 32
#define NEGV -10000000.0f

// ---------------------------------------------------------------------------
// Kernel 1: LSH bits. One wave handles 2 queries; lane = 32*which + b.
// ---------------------------------------------------------------------------
__global__ __launch_bounds__(256) void bits_kernel(const float* __restrict__ q,
                                                   const float* __restrict__ planes,
                                                   unsigned int* __restrict__ bits) {
    int tid = threadIdx.x;
    int wave = tid >> 6;
    int lane = tid & 63;
    int b = lane & 31;
    int which = lane >> 5;
    int qi = blockIdx.x * 8 + wave * 2 + which;   // qi = (n*H + h)*L + l
    int l = qi & (LB - 1);
    int nh = qi / LB;
    int h = nh & (HB - 1);
    int n = nh / HB;
    const float* qrow = q + (((long long)n * LB + l) * HB + h) * EB;  // queries (N,L,H,E)
    const float* prow = planes + b * (EB + 1);
    double acc = (double)prow[EB];                 // bias (the concatenated ones column)
    #pragma unroll 8
    for (int e = 0; e < EB; ++e) acc += (double)qrow[e] * (double)prow[e];
    unsigned long long m = __ballot(acc > 0.0);
    if (b == 0) {
        bits[qi] = (unsigned int)(which ? (m >> 32) : (m & 0xffffffffULL));
    }
}

// ---------------------------------------------------------------------------
// Kernel 2: k-means on Hamming distance. One block per (n,h). All integer /
// exact. argmin = first occurrence of min. Centroid bit: 2*sums >= cnt.
// ---------------------------------------------------------------------------
__global__ __launch_bounds__(1024) void cluster_kernel(const unsigned int* __restrict__ bits,
                                                       int* __restrict__ assign_g,
                                                       int* __restrict__ cnt_g) {
    __shared__ unsigned int bl[LB];
    __shared__ unsigned int cent[CLN];
    __shared__ int sums[CLN * BITSN];
    __shared__ int cnt[CLN];
    int nh = blockIdx.x;
    int tid = threadIdx.x;
    for (int l = tid; l < LB; l += 1024) bl[l] = bits[nh * LB + l];
    __syncthreads();
    if (tid < CLN) cent[tid] = bl[tid * (LB / CLN)];   // init_idx = c*L//C = 16c
    __syncthreads();

    for (int it = 0; it < ITERS; ++it) {
        for (int i = tid; i < CLN * BITSN; i += 1024) sums[i] = 0;
        if (tid < CLN) cnt[tid] = 0;
        __syncthreads();
        for (int l = tid; l < LB; l += 1024) {
            unsigned int bv = bl[l];
            int best = __popc(bv ^ cent[0]);
            int bc = 0;
            #pragma unroll 4
            for (int c = 1; c < CLN; ++c) {
                int d = __popc(bv ^ cent[c]);
                if (d < best) { best = d; bc = c; }
            }
            atomicAdd(&cnt[bc], 1);
            unsigned int bb = bv;
            while (bb) {
                int j = __ffs(bb) - 1;
                atomicAdd(&sums[bc * BITSN + j], 1);
                bb &= bb - 1;
            }
        }
        __syncthreads();
        if (tid < CLN) {
            int c = tid;
            int cn = cnt[c];
            if (cn > 0) {
                unsigned int nb = 0u;
                for (int j = 0; j < BITSN; ++j)
                    if (2 * sums[c * BITSN + j] >= cn) nb |= (1u << j);
                cent[c] = nb;
            }
        }
        __syncthreads();
    }

    // final (11th) assignment pass -> assign, cnt
    if (tid < CLN) cnt[tid] = 0;
    __syncthreads();
    for (int l = tid; l < LB; l += 1024) {
        unsigned int bv = bl[l];
        int best = __popc(bv ^ cent[0]);
        int bc = 0;
        #pragma unroll 4
        for (int c = 1; c < CLN; ++c) {
            int d = __popc(bv ^ cent[c]);
            if (d < best) { best = d; bc = c; }
        }
        assign_g[nh * LB + l] = bc;
        atomicAdd(&cnt[bc], 1);
    }
    __syncthreads();
    if (tid < CLN) cnt_g[nh * CLN + tid] = cnt[tid];
}

// ---------------------------------------------------------------------------
// Kernel 3: per-(n,h,c): Qg (deterministic double sums), scores (double,
// thread-per-row), top-32 via single-wave zero-barrier tournament.
// Sortable-u64 map is monotone in double, so selection (incl. lower-index
// tie-break) is identical to comparing the doubles.
// ---------------------------------------------------------------------------
__global__ __launch_bounds__(256) void topk_kernel(const float* __restrict__ q,
                                                   const float* __restrict__ kk,
                                                   const int* __restrict__ assign_g,
                                                   const int* __restrict__ cnt_g,
                                                   int* __restrict__ tki) {
    __shared__ double qg[EB];
    __shared__ double psum[4][EB];
    __shared__ unsigned long long su[LB];   // sortable scores, 16 KB
    int bid = blockIdx.x;            // nh*128 + c
    int c = bid & (CLN - 1);
    int nh = bid >> 7;
    int h = nh & (HB - 1);
    int n = nh / HB;
    int tid = threadIdx.x;
    int e = tid & 63;
    int qq = tid >> 6;
    const int* arow = assign_g + nh * LB;

    // phase A: Qg = mean of Q rows assigned to cluster c (fixed quarter order)
    double acc = 0.0;
    int l0 = qq * (LB / 4), l1 = l0 + (LB / 4);
    for (int l = l0; l < l1; ++l) {
        if (arow[l] == c)
            acc += (double)q[(((long long)n * LB + l) * HB + h) * EB + e];
    }
    psum[qq][e] = acc;
    __syncthreads();
    if (tid < EB) {
        int cn = cnt_g[nh * CLN + c];
        double dcn = (double)(cn > 0 ? cn : 1);
        qg[tid] = (psum[0][tid] + psum[1][tid] + psum[2][tid] + psum[3][tid]) / dcn;
    }
    __syncthreads();

    // phase B: thread t computes full dot for rows t, t+256, ... (8 rows)
    for (int l = tid; l < LB; l += 256) {
        const float* kr = kk + (((long long)n * LB + l) * HB + h) * EB;
        double s = 0.0;
        #pragma unroll 8
        for (int ee = 0; ee < EB; ++ee) s += qg[ee] * (double)kr[ee];
        long long sb = __double_as_longlong(s);
        unsigned long long uu = (unsigned long long)sb;
        uu = (sb < 0) ? ~uu : (uu | 0x8000000000000000ULL);  // monotone map
        su[l] = uu;
    }
    __syncthreads();

    // phase C: wave 0 tournament. lane owns su[lane*32 .. lane*32+31].
    if (tid < 64) {
        int lane = tid;
        unsigned long long bu = 0ULL; int bi = lane * 32;
        #pragma unroll 4
        for (int t = 0; t < 32; ++t) {
            unsigned long long v = su[lane * 32 + t];
            if (v > bu) { bu = v; bi = lane * 32 + t; }   // strict > keeps lowest idx
        }
        for (int r = 0; r < TOPKN; ++r) {
            unsigned long long wu = bu; int wi = bi;
            #pragma unroll
            for (int off = 1; off < 64; off <<= 1) {
                unsigned long long ou = __shfl_xor(wu, off);
                int oi = __shfl_xor(wi, off);
                if (ou > wu || (ou == wu && oi < wi)) { wu = ou; wi = oi; }
            }
            if (lane == 0) tki[bid * TOPKN + r] = wi;
            if ((wi >> 5) == lane) {       // owner: invalidate + rescan
                su[wi] = 0ULL;             // below every real score's map
                bu = 0ULL; bi = lane * 32;
                #pragma unroll 4
                for (int t = 0; t < 32; ++t) {
                    unsigned long long v = su[lane * 32 + t];
                    if (v > bu) { bu = v; bi = lane * 32 + t; }
                }
            }
        }
    }
}

// ---------------------------------------------------------------------------
// Kernel 4: gather attention. One wave per query (n,h,l).
// ---------------------------------------------------------------------------
__global__ __launch_bounds__(256) void attn_kernel(const float* __restrict__ q,
                                                   const float* __restrict__ kk,
                                                   const float* __restrict__ vv,
                                                   const int* __restrict__ assign_g,
                                                   const int* __restrict__ tki,
                                                   float* __restrict__ out) {
    int tid = threadIdx.x;
    int wave = tid >> 6, lane = tid & 63;
    int qi = blockIdx.x * 4 + wave;   // (nh)*L + l
    int l = qi & (LB - 1);
    int nh = qi / LB;
    int h = nh & (HB - 1);
    int n = nh / HB;
    int c = assign_g[qi];
    const int* krow = tki + (nh * CLN + c) * TOPKN;
    int j = lane & 31, p = lane >> 5;
    int kidx = krow[j];

    const float* qrow = q + (((long long)n * LB + l) * HB + h) * EB;
    const float* krp = kk + (((long long)n * LB + kidx) * HB + h) * EB;
    float part = 0.f;
    #pragma unroll
    for (int e = 32 * p; e < 32 * p + 32; ++e) part += qrow[e] * krp[e];
    float qlo = __shfl(part, j);
    float qhi = __shfl(part, j + 32);
    float qk = qlo + qhi;

    bool future = kidx > l;
    float logit = 0.125f * (future ? NEGV : qk);
    float m = logit;
    #pragma unroll
    for (int off = 16; off; off >>= 1) m = fmaxf(m, __shfl_xor(m, off));
    float ex = expf(logit - m);
    float ssum = ex;
    #pragma unroll
    for (int off = 16; off; off >>= 1) ssum += __shfl_xor(ssum, off);
    float a = future ? 0.f : ex / ssum;

    const float* vbase = vv + ((long long)n * LB * HB + h) * EB;  // + ki*H*E + e
    float oacc = 0.f;
    #pragma unroll 4
    for (int jj = 0; jj < TOPKN; ++jj) {
        float aj = __shfl(a, jj);
        int kj = __shfl(kidx, jj);
        if (aj != 0.f)
            oacc += aj * vbase[(long long)kj * (HB * EB) + lane];
    }
    out[(((long long)n * LB + l) * HB + h) * EB + lane] = oacc;
}

// ---------------------------------------------------------------------------
extern "C" void kernel_launch(void* const* d_in, const int* in_sizes, int n_in,
                              void* d_out, int out_size, void* d_ws, size_t ws_size,
                              hipStream_t stream) {
    const float* q = (const float*)d_in[0];
    const float* k = (const float*)d_in[1];
    const float* v = (const float*)d_in[2];
    const float* planes = (const float*)d_in[3];
    float* out = (float*)d_out;

    const int NQ = NB * HB * LB;                  // 32768
    unsigned int* bits = (unsigned int*)d_ws;
    int* assign_g = (int*)((char*)d_ws + (size_t)NQ * 4);
    int* cnt_g = (int*)((char*)d_ws + (size_t)NQ * 8);
    int* tki = (int*)((char*)d_ws + (size_t)NQ * 8 + (size_t)NB * HB * CLN * 4);

    bits_kernel<<<NQ / 8, 256, 0, stream>>>(q, planes, bits);
    cluster_kernel<<<NB * HB, 1024, 0, stream>>>(bits, assign_g, cnt_g);
    topk_kernel<<<NB * HB * CLN, 256, 0, stream>>>(q, k, assign_g, cnt_g, tki);
    attn_kernel<<<NQ / 4, 256, 0, stream>>>(q, k, v, assign_g, tki, out);
}

// Round 3
// 495.951 us; speedup vs baseline: 2.2356x; 1.0827x over previous
//
#include <hip/hip_runtime.h>
#include <math.h>

#define NB 2
#define HB 8
#define LB 2048
#define EB 64
#define BITSN 32
#define CLN 128
#define ITERS 10
#define TOPKN 32
#define NEGV -10000000.0f

typedef unsigned long long u64;
typedef unsigned int u32;

// ---------------------------------------------------------------------------
// Kernel 1: LSH bits. One wave handles 2 queries; lane = 32*which + b.
// ---------------------------------------------------------------------------
__global__ __launch_bounds__(256) void bits_kernel(const float* __restrict__ q,
                                                   const float* __restrict__ planes,
                                                   u32* __restrict__ bits) {
    int tid = threadIdx.x;
    int wave = tid >> 6;
    int lane = tid & 63;
    int b = lane & 31;
    int which = lane >> 5;
    int qi = blockIdx.x * 8 + wave * 2 + which;   // qi = (n*H + h)*L + l
    int l = qi & (LB - 1);
    int nh = qi / LB;
    int h = nh & (HB - 1);
    int n = nh / HB;
    const float* qrow = q + (((long long)n * LB + l) * HB + h) * EB;
    const float* prow = planes + b * (EB + 1);
    double acc = (double)prow[EB];                 // bias (the ones column)
    #pragma unroll 8
    for (int e = 0; e < EB; ++e) acc += (double)qrow[e] * (double)prow[e];
    unsigned long long m = __ballot(acc > 0.0);
    if (b == 0) {
        bits[qi] = (u32)(which ? (m >> 32) : (m & 0xffffffffULL));
    }
}

// ---------------------------------------------------------------------------
// Kernel 2: k-means on Hamming distance. One block per (n,h). All integer /
// exact. argmin = first occurrence of min. Centroid bit: 2*sums >= cnt.
// Adds: exact early-exit on converged assignments (remaining iterations are
// identity), per-cluster sorted member lists + prefix offsets.
// ---------------------------------------------------------------------------
__global__ __launch_bounds__(1024) void cluster_kernel(const u32* __restrict__ bits,
                                                       int* __restrict__ assign_g,
                                                       int* __restrict__ cnt_g,
                                                       int* __restrict__ ofs_g,
                                                       int* __restrict__ list_g) {
    __shared__ u32 bl[LB];
    __shared__ u32 cent[CLN];
    __shared__ int sums[CLN * BITSN];
    __shared__ int cnt[CLN];
    __shared__ unsigned char al[LB];
    __shared__ int ofs[CLN + 1];
    __shared__ int changed;
    int nh = blockIdx.x;
    int tid = threadIdx.x;
    for (int l = tid; l < LB; l += 1024) { bl[l] = bits[nh * LB + l]; al[l] = 255; }
    __syncthreads();
    if (tid < CLN) cent[tid] = bl[tid * (LB / CLN)];   // init_idx = c*L//C = 16c
    __syncthreads();

    for (int it = 0; it < ITERS; ++it) {
        for (int i = tid; i < CLN * BITSN; i += 1024) sums[i] = 0;
        if (tid < CLN) cnt[tid] = 0;
        if (tid == 0) changed = 0;
        __syncthreads();
        for (int l = tid; l < LB; l += 1024) {
            u32 bv = bl[l];
            int best = __popc(bv ^ cent[0]);
            int bc = 0;
            #pragma unroll 4
            for (int c = 1; c < CLN; ++c) {
                int d = __popc(bv ^ cent[c]);
                if (d < best) { best = d; bc = c; }
            }
            if (al[l] != (unsigned char)bc) changed = 1;   // race-benign (all write 1)
            al[l] = (unsigned char)bc;
            atomicAdd(&cnt[bc], 1);
            u32 bb = bv;
            while (bb) {
                int j = __ffs(bb) - 1;
                atomicAdd(&sums[bc * BITSN + j], 1);
                bb &= bb - 1;
            }
        }
        __syncthreads();
        if (!changed) break;     // converged: all remaining iterations identity
        if (tid < CLN) {
            int c = tid;
            int cn = cnt[c];
            if (cn > 0) {
                u32 nb = 0u;
                for (int j = 0; j < BITSN; ++j)
                    if (2 * sums[c * BITSN + j] >= cn) nb |= (1u << j);
                cent[c] = nb;
            }
        }
        __syncthreads();
    }

    // final assignment pass (reference's 11th distance computation)
    if (tid < CLN) cnt[tid] = 0;
    __syncthreads();
    for (int l = tid; l < LB; l += 1024) {
        u32 bv = bl[l];
        int best = __popc(bv ^ cent[0]);
        int bc = 0;
        #pragma unroll 4
        for (int c = 1; c < CLN; ++c) {
            int d = __popc(bv ^ cent[c]);
            if (d < best) { best = d; bc = c; }
        }
        assign_g[nh * LB + l] = bc;
        al[l] = (unsigned char)bc;
        atomicAdd(&cnt[bc], 1);
    }
    __syncthreads();
    if (tid == 0) {
        ofs[0] = 0;
        for (int c = 0; c < CLN; ++c) ofs[c + 1] = ofs[c] + cnt[c];
    }
    __syncthreads();
    if (tid < CLN) {
        cnt_g[nh * CLN + tid] = cnt[tid];
        ofs_g[nh * CLN + tid] = ofs[tid];
        // stable (ascending-l) member list for cluster tid
        int p = ofs[tid];
        for (int l = 0; l < LB; ++l)
            if (al[l] == (unsigned char)tid) list_g[nh * LB + p++] = l;
    }
}

// ---------------------------------------------------------------------------
// Kernel 3a: Qg per (n,h,c) via member list. f64 ascending-l sum (exactly the
// reference's einsum order class), stored f32. One wave per block.
// ---------------------------------------------------------------------------
__global__ __launch_bounds__(64) void qg_kernel(const float* __restrict__ q,
                                                const int* __restrict__ cnt_g,
                                                const int* __restrict__ ofs_g,
                                                const int* __restrict__ list_g,
                                                float* __restrict__ qgf) {
    int bid = blockIdx.x;            // nh*128 + c
    int nh = bid >> 7;
    int h = nh & (HB - 1);
    int n = nh / HB;
    int e = threadIdx.x;
    int cn = cnt_g[bid];
    int o = ofs_g[bid];
    const int* lp = list_g + nh * LB + o;
    double acc = 0.0;
    for (int i = 0; i < cn; ++i) {
        int l = lp[i];
        acc += (double)q[(((long long)n * LB + l) * HB + h) * EB + e];
    }
    double dcn = (double)(cn > 0 ? cn : 1);
    qgf[(long long)bid * EB + e] = (float)(acc / dcn);
}

// ---------------------------------------------------------------------------
// Kernel 3b: scores. Block per (nh, 128-row tile) -> K read exactly once.
// Lane holds its K row in 64 VGPRs; loops 64 clusters with wave-uniform Qg
// reads (scalarizable). Writes sortable-u32 keys.
// ---------------------------------------------------------------------------
__global__ __launch_bounds__(256) void scores_kernel(const float* __restrict__ kk,
                                                     const float* __restrict__ qgf,
                                                     u32* __restrict__ keys) {
    int bid = blockIdx.x;            // nh*16 + tile
    int nh = bid >> 4;
    int tile = bid & 15;
    int h = nh & (HB - 1);
    int n = nh / HB;
    int w = threadIdx.x >> 6;
    int lane = threadIdx.x & 63;
    int rl = (w & 1) * 64 + lane;    // row within tile
    int l = tile * 128 + rl;
    int cbase = (w >> 1) * 64;       // waves 0,1: c 0-63; waves 2,3: c 64-127

    const float4* kr4 = (const float4*)(kk + (((long long)n * LB + l) * HB + h) * EB);
    float rr[EB];
    #pragma unroll
    for (int i = 0; i < 16; ++i) {
        float4 t4 = kr4[i];
        rr[4 * i] = t4.x; rr[4 * i + 1] = t4.y; rr[4 * i + 2] = t4.z; rr[4 * i + 3] = t4.w;
    }
    const float* qp0 = qgf + ((long long)nh * CLN + cbase) * EB;
    for (int c = 0; c < 64; ++c) {
        const float4* qp = (const float4*)(qp0 + c * EB);   // wave-uniform address
        float acc = 0.f;
        #pragma unroll
        for (int i = 0; i < 16; ++i) {
            float4 qv = qp[i];
            acc = fmaf(qv.x, rr[4 * i], acc);
            acc = fmaf(qv.y, rr[4 * i + 1], acc);
            acc = fmaf(qv.z, rr[4 * i + 2], acc);
            acc = fmaf(qv.w, rr[4 * i + 3], acc);
        }
        u32 u = __float_as_uint(acc);
        u = ((int)u < 0) ? ~u : (u | 0x80000000u);          // monotone f32->u32
        keys[((long long)(nh * CLN + cbase + c)) * LB + l] = u;
    }
}

// ---------------------------------------------------------------------------
// Kernel 3c: top-32 per (n,h,c). One wave; 32 keys/lane in registers packed
// (key<<32)|(2047-l) -> single u64 compare = (value desc, index asc) order,
// matching lax.top_k. Implicit-deletion rescan: max over {k : k < winner}.
// ---------------------------------------------------------------------------
__global__ __launch_bounds__(64) void topsel_kernel(const u32* __restrict__ keys,
                                                    int* __restrict__ tki) {
    int bid = blockIdx.x;            // nh*128 + c
    int lane = threadIdx.x;
    const uint4* kp4 = (const uint4*)(keys + (long long)bid * LB);
    u64 k[32];
    #pragma unroll
    for (int t = 0; t < 8; ++t) {
        uint4 kv = kp4[lane + 64 * t];
        int l0 = (lane + 64 * t) * 4;
        k[4 * t]     = ((u64)kv.x << 32) | (u32)(2047 - l0);
        k[4 * t + 1] = ((u64)kv.y << 32) | (u32)(2047 - (l0 + 1));
        k[4 * t + 2] = ((u64)kv.z << 32) | (u32)(2047 - (l0 + 2));
        k[4 * t + 3] = ((u64)kv.w << 32) | (u32)(2047 - (l0 + 3));
    }
    // initial per-lane max (4 independent chains of 8, then combine)
    u64 m0 = k[0], m1 = k[8], m2 = k[16], m3 = k[24];
    #pragma unroll
    for (int t = 1; t < 8; ++t) {
        if (k[t] > m0) m0 = k[t];
        if (k[8 + t] > m1) m1 = k[8 + t];
        if (k[16 + t] > m2) m2 = k[16 + t];
        if (k[24 + t] > m3) m3 = k[24 + t];
    }
    if (m1 > m0) m0 = m1;
    if (m3 > m2) m2 = m3;
    u64 cur = (m2 > m0) ? m2 : m0;

    for (int r = 0; r < TOPKN; ++r) {
        u64 wk = cur;
        #pragma unroll
        for (int off = 1; off < 64; off <<= 1) {
            u64 o = __shfl_xor(wk, off);
            if (o > wk) wk = o;
        }
        if (lane == 0) tki[bid * TOPKN + r] = 2047 - (int)(wk & 2047u);
        if (wk == cur) {               // unique owner (indices embedded)
            u64 nm = 0ULL;
            #pragma unroll
            for (int t = 0; t < 32; ++t) {
                u64 kt = k[t];
                u64 cand = (kt < wk) ? kt : 0ULL;   // deleted keys are >= wk
                if (cand > nm) nm = cand;
            }
            cur = nm;
        }
    }
}

// ---------------------------------------------------------------------------
// Kernel 4: gather attention. One wave per query (n,h,l). QK via dwordx4.
// ---------------------------------------------------------------------------
__global__ __launch_bounds__(256) void attn_kernel(const float* __restrict__ q,
                                                   const float* __restrict__ kk,
                                                   const float* __restrict__ vv,
                                                   const int* __restrict__ assign_g,
                                                   const int* __restrict__ tki,
                                                   float* __restrict__ out) {
    int tid = threadIdx.x;
    int wave = tid >> 6, lane = tid & 63;
    int qi = blockIdx.x * 4 + wave;   // (nh)*L + l
    int l = qi & (LB - 1);
    int nh = qi / LB;
    int h = nh & (HB - 1);
    int n = nh / HB;
    int c = assign_g[qi];
    const int* krow = tki + (nh * CLN + c) * TOPKN;
    int j = lane & 31, p = lane >> 5;
    int kidx = krow[j];

    const float4* q4 = (const float4*)(q + (((long long)n * LB + l) * HB + h) * EB) + p * 8;
    const float4* k4 = (const float4*)(kk + (((long long)n * LB + kidx) * HB + h) * EB) + p * 8;
    float part = 0.f;
    #pragma unroll
    for (int i = 0; i < 8; ++i) {
        float4 a = q4[i], b = k4[i];
        part += a.x * b.x + a.y * b.y + a.z * b.z + a.w * b.w;
    }
    float qlo = __shfl(part, j);
    float qhi = __shfl(part, j + 32);
    float qk = qlo + qhi;

    bool future = kidx > l;
    float logit = 0.125f * (future ? NEGV : qk);
    float m = logit;
    #pragma unroll
    for (int off = 16; off; off >>= 1) m = fmaxf(m, __shfl_xor(m, off));
    float ex = expf(logit - m);
    float ssum = ex;
    #pragma unroll
    for (int off = 16; off; off >>= 1) ssum += __shfl_xor(ssum, off);
    float a = future ? 0.f : ex / ssum;

    const float* vbase = vv + ((long long)n * LB * HB + h) * EB;  // + ki*H*E + e
    float oacc = 0.f;
    #pragma unroll 4
    for (int jj = 0; jj < TOPKN; ++jj) {
        float aj = __shfl(a, jj);
        int kj = __shfl(kidx, jj);
        if (aj != 0.f)   // wave-uniform
            oacc += aj * vbase[(long long)kj * (HB * EB) + lane];
    }
    out[(((long long)n * LB + l) * HB + h) * EB + lane] = oacc;
}

// ---------------------------------------------------------------------------
extern "C" void kernel_launch(void* const* d_in, const int* in_sizes, int n_in,
                              void* d_out, int out_size, void* d_ws, size_t ws_size,
                              hipStream_t stream) {
    const float* q = (const float*)d_in[0];
    const float* k = (const float*)d_in[1];
    const float* v = (const float*)d_in[2];
    const float* planes = (const float*)d_in[3];
    float* out = (float*)d_out;

    const int NQ = NB * HB * LB;                  // 32768
    char* ws = (char*)d_ws;
    u32* bits     = (u32*)(ws);                    // 128 KB
    int* assign_g = (int*)(ws + 0x20000);          // 128 KB
    int* cnt_g    = (int*)(ws + 0x40000);          // 8 KB
    int* ofs_g    = (int*)(ws + 0x42000);          // 8 KB
    int* list_g   = (int*)(ws + 0x44000);          // 128 KB
    float* qgf    = (float*)(ws + 0x64000);        // 512 KB
    int* tki      = (int*)(ws + 0xE4000);          // 256 KB
    u32* keys     = (u32*)(ws + 0x124000);         // 16 MB

    bits_kernel<<<NQ / 8, 256, 0, stream>>>(q, planes, bits);
    cluster_kernel<<<NB * HB, 1024, 0, stream>>>(bits, assign_g, cnt_g, ofs_g, list_g);
    qg_kernel<<<NB * HB * CLN, 64, 0, stream>>>(q, cnt_g, ofs_g, list_g, qgf);
    scores_kernel<<<NB * HB * 16, 256, 0, stream>>>(k, qgf, keys);
    topsel_kernel<<<NB * HB * CLN, 64, 0, stream>>>(keys, tki);
    attn_kernel<<<NQ / 4, 256, 0, stream>>>(q, k, v, assign_g, tki, out);
}